// Round 1
// baseline (1558.906 us; speedup 1.0000x reference)
//
#include <hip/hip_runtime.h>
#include <hip/hip_bf16.h>

#define BATCH 512
#define NNODE 131072
#define NEDGE 131072

// Generic 32x32 tiled transpose: in is (R, C) row-major, out is (C, R).
__global__ void transpose_k(const float* __restrict__ in, float* __restrict__ out,
                            int R, int C) {
    __shared__ float tile[32][33];
    int c0 = blockIdx.x * 32;
    int r0 = blockIdx.y * 32;
    int tx = threadIdx.x;   // 0..31
    int ty = threadIdx.y;   // 0..7
#pragma unroll
    for (int i = 0; i < 32; i += 8) {
        tile[ty + i][tx] = in[(size_t)(r0 + ty + i) * C + (c0 + tx)];
    }
    __syncthreads();
#pragma unroll
    for (int i = 0; i < 32; i += 8) {
        out[(size_t)(c0 + ty + i) * R + (r0 + tx)] = tile[tx][ty + i];
    }
}

// One block per edge. cur/out are (N, B) so a column is 512 contiguous floats.
// out must already contain a copy of cur; we add cur[:, src] into out[:, dst].
__global__ void scatter_k(const float* __restrict__ cur, float* __restrict__ out,
                          const int* __restrict__ edges) {
    int e = blockIdx.x;
    int s = edges[e];          // row 0: src
    int d = edges[NEDGE + e];  // row 1: dst
    const float* sc = cur + (size_t)s * BATCH;
    float* dc = out + (size_t)d * BATCH;
    int b = threadIdx.x;       // 0..511
    atomicAdd(&dc[b], sc[b]);
}

extern "C" void kernel_launch(void* const* d_in, const int* in_sizes, int n_in,
                              void* d_out, int out_size, void* d_ws, size_t ws_size,
                              hipStream_t stream) {
    const float* x  = (const float*)d_in[0];
    const int* e0   = (const int*)d_in[1];
    const int* e1   = (const int*)d_in[2];
    const int* e2   = (const int*)d_in[3];
    const int* e3   = (const int*)d_in[4];

    float* T0 = (float*)d_ws;    // transposed scratch A (needs N*B*4 = 256 MB)
    float* T1 = (float*)d_out;   // use d_out as transposed scratch B until the end

    const size_t bytes = (size_t)NNODE * BATCH * sizeof(float);
    dim3 blk(32, 8);

    // x (B,N) -> T0 (N,B)
    transpose_k<<<dim3(NNODE / 32, BATCH / 32), blk, 0, stream>>>(x, T0, BATCH, NNODE);

    // Layers applied in reference order: edges3, edges2, edges1, edges0
    const int* order[4] = {e3, e2, e1, e0};
    float* cur = T0;
    float* nxt = T1;
    for (int L = 0; L < 4; ++L) {
        hipMemcpyAsync(nxt, cur, bytes, hipMemcpyDeviceToDevice, stream);
        scatter_k<<<NEDGE, BATCH, 0, stream>>>(cur, nxt, order[L]);
        float* t = cur; cur = nxt; nxt = t;
    }
    // After 4 swaps cur == T0 (d_ws). Transpose back (N,B) -> (B,N) into d_out.
    transpose_k<<<dim3(BATCH / 32, NNODE / 32), blk, 0, stream>>>(cur, (float*)d_out, NNODE, BATCH);
}

// Round 2
// 1248.027 us; speedup vs baseline: 1.2491x; 1.2491x over previous
//
#include <hip/hip_runtime.h>
#include <hip/hip_bf16.h>

#define BATCH 512
#define NNODE 131072
#define NEDGE 131072
#define SCAN_BLK 1024
#define SCAN_NBLK (NNODE / SCAN_BLK)   // 128

// CSR scratch in static device memory (~2.3 MB, zero-init .bss)
__device__ int g_counts[NNODE];
__device__ int g_offs[NNODE];
__device__ int g_cursor[NNODE];
__device__ int g_srcl[NEDGE];
__device__ int g_bsums[SCAN_NBLK];

// ---- 32x32 tiled transpose, float4 wide. in: (R,C) row-major -> out: (C,R).
// blockDim = (8, 32)
__global__ void transpose_k(const float* __restrict__ in, float* __restrict__ out,
                            int R, int C) {
    __shared__ float tile[32][33];
    int c0 = blockIdx.x * 32;
    int r0 = blockIdx.y * 32;
    int tx = threadIdx.x;   // 0..7
    int ty = threadIdx.y;   // 0..31
    float4 v = *reinterpret_cast<const float4*>(&in[(size_t)(r0 + ty) * C + c0 + 4 * tx]);
    tile[ty][4 * tx + 0] = v.x;
    tile[ty][4 * tx + 1] = v.y;
    tile[ty][4 * tx + 2] = v.z;
    tile[ty][4 * tx + 3] = v.w;
    __syncthreads();
    float4 w;
    w.x = tile[4 * tx + 0][ty];
    w.y = tile[4 * tx + 1][ty];
    w.z = tile[4 * tx + 2][ty];
    w.w = tile[4 * tx + 3][ty];
    *reinterpret_cast<float4*>(&out[(size_t)(c0 + ty) * R + r0 + 4 * tx]) = w;
}

// ---- CSR build ----
__global__ void zero_counts_k() {
    int i = blockIdx.x * blockDim.x + threadIdx.x;
    g_counts[i] = 0;
}

__global__ void hist_k(const int* __restrict__ edges) {
    int e = blockIdx.x * blockDim.x + threadIdx.x;
    atomicAdd(&g_counts[edges[NEDGE + e]], 1);
}

// block-level exclusive scan of counts -> offs, block totals -> bsums
__global__ void scan_block_k() {
    __shared__ int sh[SCAN_BLK];
    int t = threadIdx.x;
    int i = blockIdx.x * SCAN_BLK + t;
    int own = g_counts[i];
    sh[t] = own;
    __syncthreads();
    for (int off = 1; off < SCAN_BLK; off <<= 1) {
        int v = (t >= off) ? sh[t - off] : 0;
        __syncthreads();
        sh[t] += v;
        __syncthreads();
    }
    g_offs[i] = sh[t] - own;              // exclusive
    if (t == SCAN_BLK - 1) g_bsums[blockIdx.x] = sh[t];
}

__global__ void scan_bsums_k() {
    __shared__ int sh[SCAN_NBLK];
    int t = threadIdx.x;
    int own = g_bsums[t];
    sh[t] = own;
    __syncthreads();
    for (int off = 1; off < SCAN_NBLK; off <<= 1) {
        int v = (t >= off) ? sh[t - off] : 0;
        __syncthreads();
        sh[t] += v;
        __syncthreads();
    }
    g_bsums[t] = sh[t] - own;             // exclusive
}

__global__ void scan_add_k() {
    int i = blockIdx.x * SCAN_BLK + threadIdx.x;
    int o = g_offs[i] + g_bsums[blockIdx.x];
    g_offs[i] = o;
    g_cursor[i] = o;
}

__global__ void fill_k(const int* __restrict__ edges) {
    int e = blockIdx.x * blockDim.x + threadIdx.x;
    int s = edges[e];
    int d = edges[NEDGE + e];
    int p = atomicAdd(&g_cursor[d], 1);
    g_srcl[p] = s;
}

// ---- gather: one block per node, cur/out are (N, B) ----
__global__ void gather_k(const float* __restrict__ cur, float* __restrict__ out) {
    int n = blockIdx.x;
    int t = threadIdx.x;
    int beg = g_offs[n];
    int deg = g_counts[n];
    float acc = cur[(size_t)n * BATCH + t];
    for (int j = 0; j < deg; ++j) {
        int s = g_srcl[beg + j];
        acc += cur[(size_t)s * BATCH + t];
    }
    out[(size_t)n * BATCH + t] = acc;
}

extern "C" void kernel_launch(void* const* d_in, const int* in_sizes, int n_in,
                              void* d_out, int out_size, void* d_ws, size_t ws_size,
                              hipStream_t stream) {
    const float* x = (const float*)d_in[0];
    const int* order[4] = {(const int*)d_in[4], (const int*)d_in[3],
                           (const int*)d_in[2], (const int*)d_in[1]};  // edges3..edges0

    float* T0 = (float*)d_ws;    // transposed scratch A (256 MB)
    float* T1 = (float*)d_out;   // d_out doubles as transposed scratch B

    dim3 tblk(8, 32);

    // x (B,N) -> T0 (N,B)
    transpose_k<<<dim3(NNODE / 32, BATCH / 32), tblk, 0, stream>>>(x, T0, BATCH, NNODE);

    float* cur = T0;
    float* nxt = T1;
    for (int L = 0; L < 4; ++L) {
        const int* edges = order[L];
        zero_counts_k<<<NNODE / 512, 512, 0, stream>>>();
        hist_k<<<NEDGE / 512, 512, 0, stream>>>(edges);
        scan_block_k<<<SCAN_NBLK, SCAN_BLK, 0, stream>>>();
        scan_bsums_k<<<1, SCAN_NBLK, 0, stream>>>();
        scan_add_k<<<SCAN_NBLK, SCAN_BLK, 0, stream>>>();
        fill_k<<<NEDGE / 512, 512, 0, stream>>>(edges);
        gather_k<<<NNODE, BATCH, 0, stream>>>(cur, nxt);
        float* t = cur; cur = nxt; nxt = t;
    }
    // After 4 swaps cur == T0 (d_ws). Transpose back (N,B) -> (B,N) into d_out.
    transpose_k<<<dim3(BATCH / 32, NNODE / 32), tblk, 0, stream>>>(cur, (float*)d_out, NNODE, BATCH);
}

// Round 3
// 750.955 us; speedup vs baseline: 2.0759x; 1.6619x over previous
//
#include <hip/hip_runtime.h>
#include <hip/hip_bf16.h>

#define BATCH 512
#define NNODE 131072
#define NEDGE 131072
#define NLAYER 4
#define SCAN_BLK 1024
#define SCAN_NBLK (NNODE / SCAN_BLK)   // 128

// CSR scratch for all 4 layers in static device memory (~8 MB)
__device__ int g_counts[NLAYER][NNODE];
__device__ int g_offs[NLAYER][NNODE];
__device__ int g_cursor[NLAYER][NNODE];
__device__ int g_srcl[NLAYER][NEDGE];
__device__ int g_bsums[NLAYER][SCAN_NBLK];

// ---- 32x32 tiled transpose, float4 wide. in: (R,C) row-major -> out: (C,R).
// blockDim = (8, 32)
__global__ void transpose_k(const float* __restrict__ in, float* __restrict__ out,
                            int R, int C) {
    __shared__ float tile[32][33];
    int c0 = blockIdx.x * 32;
    int r0 = blockIdx.y * 32;
    int tx = threadIdx.x;   // 0..7
    int ty = threadIdx.y;   // 0..31
    float4 v = *reinterpret_cast<const float4*>(&in[(size_t)(r0 + ty) * C + c0 + 4 * tx]);
    tile[ty][4 * tx + 0] = v.x;
    tile[ty][4 * tx + 1] = v.y;
    tile[ty][4 * tx + 2] = v.z;
    tile[ty][4 * tx + 3] = v.w;
    __syncthreads();
    float4 w;
    w.x = tile[4 * tx + 0][ty];
    w.y = tile[4 * tx + 1][ty];
    w.z = tile[4 * tx + 2][ty];
    w.w = tile[4 * tx + 3][ty];
    *reinterpret_cast<float4*>(&out[(size_t)(c0 + ty) * R + r0 + 4 * tx]) = w;
}

// ---- fused CSR build (all 4 layers) ----
__global__ void zero_counts_k() {
    int i = blockIdx.x * blockDim.x + threadIdx.x;   // 0 .. 4N
    ((int*)g_counts)[i] = 0;
}

__global__ void hist_k(const int* __restrict__ p0, const int* __restrict__ p1,
                       const int* __restrict__ p2, const int* __restrict__ p3) {
    int i = blockIdx.x * blockDim.x + threadIdx.x;   // 0 .. 4E
    int layer = i >> 17;                             // NEDGE = 2^17
    int e = i & (NEDGE - 1);
    const int* eg = layer == 0 ? p0 : layer == 1 ? p1 : layer == 2 ? p2 : p3;
    atomicAdd(&g_counts[layer][eg[NEDGE + e]], 1);
}

// block-level exclusive scan of counts -> offs, block totals -> bsums
__global__ void scan_block_k() {
    __shared__ int sh[SCAN_BLK];
    int layer = blockIdx.x / SCAN_NBLK;
    int blk = blockIdx.x % SCAN_NBLK;
    int t = threadIdx.x;
    int i = blk * SCAN_BLK + t;
    int own = g_counts[layer][i];
    sh[t] = own;
    __syncthreads();
    for (int off = 1; off < SCAN_BLK; off <<= 1) {
        int v = (t >= off) ? sh[t - off] : 0;
        __syncthreads();
        sh[t] += v;
        __syncthreads();
    }
    g_offs[layer][i] = sh[t] - own;              // exclusive
    if (t == SCAN_BLK - 1) g_bsums[layer][blk] = sh[t];
}

__global__ void scan_bsums_k() {
    __shared__ int sh[SCAN_NBLK];
    int layer = blockIdx.x;
    int t = threadIdx.x;
    int own = g_bsums[layer][t];
    sh[t] = own;
    __syncthreads();
    for (int off = 1; off < SCAN_NBLK; off <<= 1) {
        int v = (t >= off) ? sh[t - off] : 0;
        __syncthreads();
        sh[t] += v;
        __syncthreads();
    }
    g_bsums[layer][t] = sh[t] - own;             // exclusive
}

__global__ void scan_add_k() {
    int layer = blockIdx.x / SCAN_NBLK;
    int blk = blockIdx.x % SCAN_NBLK;
    int i = blk * SCAN_BLK + threadIdx.x;
    int o = g_offs[layer][i] + g_bsums[layer][blk];
    g_offs[layer][i] = o;
    g_cursor[layer][i] = o;
}

__global__ void fill_k(const int* __restrict__ p0, const int* __restrict__ p1,
                       const int* __restrict__ p2, const int* __restrict__ p3) {
    int i = blockIdx.x * blockDim.x + threadIdx.x;
    int layer = i >> 17;
    int e = i & (NEDGE - 1);
    const int* eg = layer == 0 ? p0 : layer == 1 ? p1 : layer == 2 ? p2 : p3;
    int s = eg[e];
    int d = eg[NEDGE + e];
    int p = atomicAdd(&g_cursor[layer][d], 1);
    g_srcl[layer][p] = s;
}

// ---- gather: 8 nodes per 512-thread block; each thread owns 2 float4 slots
// (2 independent chains, 2 KB per wave-load) ----
__global__ void gather_k(const float4* __restrict__ cur, float4* __restrict__ out,
                         int layer) {
    int t = threadIdx.x;
    int n = blockIdx.x * 8 + (t >> 6);
    int q = t & 63;
    int beg = g_offs[layer][n];
    int deg = g_counts[layer][n];
    size_t base = (size_t)n * 128 + q;
    float4 a0 = cur[base];
    float4 a1 = cur[base + 64];
    const int* sl = &g_srcl[layer][beg];
    for (int j = 0; j < deg; ++j) {
        size_t sb = (size_t)sl[j] * 128 + q;
        float4 v0 = cur[sb];
        float4 v1 = cur[sb + 64];
        a0.x += v0.x; a0.y += v0.y; a0.z += v0.z; a0.w += v0.w;
        a1.x += v1.x; a1.y += v1.y; a1.z += v1.z; a1.w += v1.w;
    }
    out[base] = a0;
    out[base + 64] = a1;
}

extern "C" void kernel_launch(void* const* d_in, const int* in_sizes, int n_in,
                              void* d_out, int out_size, void* d_ws, size_t ws_size,
                              hipStream_t stream) {
    const float* x = (const float*)d_in[0];
    // Application order: edges3 (layer 0) ... edges0 (layer 3)
    const int* p0 = (const int*)d_in[4];
    const int* p1 = (const int*)d_in[3];
    const int* p2 = (const int*)d_in[2];
    const int* p3 = (const int*)d_in[1];

    float* T0 = (float*)d_ws;    // transposed scratch A (256 MB)
    float* T1 = (float*)d_out;   // d_out doubles as transposed scratch B

    // CSR build for all 4 layers (independent of x)
    zero_counts_k<<<NLAYER * NNODE / 1024, 1024, 0, stream>>>();
    hist_k<<<NLAYER * NEDGE / 1024, 1024, 0, stream>>>(p0, p1, p2, p3);
    scan_block_k<<<NLAYER * SCAN_NBLK, SCAN_BLK, 0, stream>>>();
    scan_bsums_k<<<NLAYER, SCAN_NBLK, 0, stream>>>();
    scan_add_k<<<NLAYER * SCAN_NBLK, SCAN_BLK, 0, stream>>>();
    fill_k<<<NLAYER * NEDGE / 1024, 1024, 0, stream>>>(p0, p1, p2, p3);

    dim3 tblk(8, 32);
    // x (B,N) -> T0 (N,B)
    transpose_k<<<dim3(NNODE / 32, BATCH / 32), tblk, 0, stream>>>(x, T0, BATCH, NNODE);

    float* cur = T0;
    float* nxt = T1;
    for (int L = 0; L < NLAYER; ++L) {
        gather_k<<<NNODE / 8, 512, 0, stream>>>((const float4*)cur, (float4*)nxt, L);
        float* t = cur; cur = nxt; nxt = t;
    }
    // After 4 swaps cur == T0 (d_ws). Transpose back (N,B) -> (B,N) into d_out.
    transpose_k<<<dim3(BATCH / 32, NNODE / 32), tblk, 0, stream>>>(cur, (float*)d_out, NNODE, BATCH);
}

// Round 4
// 731.569 us; speedup vs baseline: 2.1309x; 1.0265x over previous
//
#include <hip/hip_runtime.h>
#include <hip/hip_bf16.h>

#define BATCH 512
#define NNODE 131072
#define NEDGE 131072
#define NLAYER 4
#define SCAN_BLK 1024
#define SCAN_NBLK (NNODE / SCAN_BLK)   // 128

// CSR scratch for all 4 layers in static device memory (~8 MB)
__device__ int g_counts[NLAYER][NNODE];
__device__ int g_offs[NLAYER][NNODE];
__device__ int g_cursor[NLAYER][NNODE];
__device__ int g_srcl[NLAYER][NEDGE];
__device__ int g_bsums[NLAYER][SCAN_NBLK];

// ---- 64x64 tiled transpose, float4 wide, 4 rows/thread (deep in-flight).
// in: (R,C) row-major -> out: (C,R). blockDim = (16,16).
__global__ void transpose_k(const float* __restrict__ in, float* __restrict__ out,
                            int R, int C) {
    __shared__ float tile[64][65];
    int c0 = blockIdx.x * 64;
    int r0 = blockIdx.y * 64;
    int tx = threadIdx.x;   // 0..15 (float4 across 64 cols)
    int ty = threadIdx.y;   // 0..15 (4 rows each, stride 16)
    float4 v[4];
#pragma unroll
    for (int i = 0; i < 4; ++i)
        v[i] = *reinterpret_cast<const float4*>(&in[(size_t)(r0 + ty + 16 * i) * C + c0 + 4 * tx]);
#pragma unroll
    for (int i = 0; i < 4; ++i) {
        tile[ty + 16 * i][4 * tx + 0] = v[i].x;
        tile[ty + 16 * i][4 * tx + 1] = v[i].y;
        tile[ty + 16 * i][4 * tx + 2] = v[i].z;
        tile[ty + 16 * i][4 * tx + 3] = v[i].w;
    }
    __syncthreads();
#pragma unroll
    for (int i = 0; i < 4; ++i) {
        float4 w;
        w.x = tile[4 * tx + 0][ty + 16 * i];
        w.y = tile[4 * tx + 1][ty + 16 * i];
        w.z = tile[4 * tx + 2][ty + 16 * i];
        w.w = tile[4 * tx + 3][ty + 16 * i];
        *reinterpret_cast<float4*>(&out[(size_t)(c0 + ty + 16 * i) * R + r0 + 4 * tx]) = w;
    }
}

// ---- fused CSR build (all 4 layers) ----
__global__ void zero_counts_k() {
    int i = blockIdx.x * blockDim.x + threadIdx.x;   // 0 .. 4N
    ((int*)g_counts)[i] = 0;
}

__global__ void hist_k(const int* __restrict__ p0, const int* __restrict__ p1,
                       const int* __restrict__ p2, const int* __restrict__ p3) {
    int i = blockIdx.x * blockDim.x + threadIdx.x;   // 0 .. 4E
    int layer = i >> 17;                             // NEDGE = 2^17
    int e = i & (NEDGE - 1);
    const int* eg = layer == 0 ? p0 : layer == 1 ? p1 : layer == 2 ? p2 : p3;
    atomicAdd(&g_counts[layer][eg[NEDGE + e]], 1);
}

__global__ void scan_block_k() {
    __shared__ int sh[SCAN_BLK];
    int layer = blockIdx.x / SCAN_NBLK;
    int blk = blockIdx.x % SCAN_NBLK;
    int t = threadIdx.x;
    int i = blk * SCAN_BLK + t;
    int own = g_counts[layer][i];
    sh[t] = own;
    __syncthreads();
    for (int off = 1; off < SCAN_BLK; off <<= 1) {
        int v = (t >= off) ? sh[t - off] : 0;
        __syncthreads();
        sh[t] += v;
        __syncthreads();
    }
    g_offs[layer][i] = sh[t] - own;              // exclusive
    if (t == SCAN_BLK - 1) g_bsums[layer][blk] = sh[t];
}

__global__ void scan_bsums_k() {
    __shared__ int sh[SCAN_NBLK];
    int layer = blockIdx.x;
    int t = threadIdx.x;
    int own = g_bsums[layer][t];
    sh[t] = own;
    __syncthreads();
    for (int off = 1; off < SCAN_NBLK; off <<= 1) {
        int v = (t >= off) ? sh[t - off] : 0;
        __syncthreads();
        sh[t] += v;
        __syncthreads();
    }
    g_bsums[layer][t] = sh[t] - own;             // exclusive
}

__global__ void scan_add_k() {
    int layer = blockIdx.x / SCAN_NBLK;
    int blk = blockIdx.x % SCAN_NBLK;
    int i = blk * SCAN_BLK + threadIdx.x;
    int o = g_offs[layer][i] + g_bsums[layer][blk];
    g_offs[layer][i] = o;
    g_cursor[layer][i] = o;
}

__global__ void fill_k(const int* __restrict__ p0, const int* __restrict__ p1,
                       const int* __restrict__ p2, const int* __restrict__ p3) {
    int i = blockIdx.x * blockDim.x + threadIdx.x;
    int layer = i >> 17;
    int e = i & (NEDGE - 1);
    const int* eg = layer == 0 ? p0 : layer == 1 ? p1 : layer == 2 ? p2 : p3;
    int s = eg[e];
    int d = eg[NEDGE + e];
    int p = atomicAdd(&g_cursor[layer][d], 1);
    g_srcl[layer][p] = s;
}

// ---- gather: 8 nodes per 512-thread block; each thread owns 2 float4 slots ----
__global__ void gather_k(const float4* __restrict__ cur, float4* __restrict__ out,
                         int layer) {
    int t = threadIdx.x;
    int n = blockIdx.x * 8 + (t >> 6);
    int q = t & 63;
    int beg = g_offs[layer][n];
    int deg = g_counts[layer][n];
    size_t base = (size_t)n * 128 + q;
    float4 a0 = cur[base];
    float4 a1 = cur[base + 64];
    const int* sl = &g_srcl[layer][beg];
    for (int j = 0; j < deg; ++j) {
        size_t sb = (size_t)sl[j] * 128 + q;
        float4 v0 = cur[sb];
        float4 v1 = cur[sb + 64];
        a0.x += v0.x; a0.y += v0.y; a0.z += v0.z; a0.w += v0.w;
        a1.x += v1.x; a1.y += v1.y; a1.z += v1.z; a1.w += v1.w;
    }
    out[base] = a0;
    out[base + 64] = a1;
}

// ---- last layer: gather 16 nodes, stage in LDS, write d_out in (B,N) layout.
// cur is (N,B) float4; out is (B,N) float. Block = 512 threads, 16 nodes.
__global__ void gather_tr_k(const float4* __restrict__ cur, float* __restrict__ out,
                            int layer) {
    __shared__ float lds[16][513];
    int t = threadIdx.x;
    int n0 = blockIdx.x * 16;
    int q = t & 63;
    int ndl = t >> 6;           // 0..7
#pragma unroll
    for (int it = 0; it < 2; ++it) {
        int nn = it * 8 + ndl;
        int n = n0 + nn;
        int beg = g_offs[layer][n];
        int deg = g_counts[layer][n];
        size_t base = (size_t)n * 128 + q;
        float4 a0 = cur[base];
        float4 a1 = cur[base + 64];
        const int* sl = &g_srcl[layer][beg];
        for (int j = 0; j < deg; ++j) {
            size_t sb = (size_t)sl[j] * 128 + q;
            float4 v0 = cur[sb];
            float4 v1 = cur[sb + 64];
            a0.x += v0.x; a0.y += v0.y; a0.z += v0.z; a0.w += v0.w;
            a1.x += v1.x; a1.y += v1.y; a1.z += v1.z; a1.w += v1.w;
        }
        lds[nn][4 * q + 0] = a0.x;
        lds[nn][4 * q + 1] = a0.y;
        lds[nn][4 * q + 2] = a0.z;
        lds[nn][4 * q + 3] = a0.w;
        lds[nn][256 + 4 * q + 0] = a1.x;
        lds[nn][256 + 4 * q + 1] = a1.y;
        lds[nn][256 + 4 * q + 2] = a1.z;
        lds[nn][256 + 4 * q + 3] = a1.w;
    }
    __syncthreads();
    // thread t owns row b = t; writes 16 contiguous floats (4 float4)
    int b = t;
    float4* orow = reinterpret_cast<float4*>(&out[(size_t)b * NNODE + n0]);
#pragma unroll
    for (int k = 0; k < 4; ++k) {
        float4 w;
        w.x = lds[4 * k + 0][b];
        w.y = lds[4 * k + 1][b];
        w.z = lds[4 * k + 2][b];
        w.w = lds[4 * k + 3][b];
        orow[k] = w;
    }
}

extern "C" void kernel_launch(void* const* d_in, const int* in_sizes, int n_in,
                              void* d_out, int out_size, void* d_ws, size_t ws_size,
                              hipStream_t stream) {
    const float* x = (const float*)d_in[0];
    // Application order: edges3 (layer 0) ... edges0 (layer 3)
    const int* p0 = (const int*)d_in[4];
    const int* p1 = (const int*)d_in[3];
    const int* p2 = (const int*)d_in[2];
    const int* p3 = (const int*)d_in[1];

    float* WS = (float*)d_ws;    // (N,B) scratch (256 MB)
    float* OUT = (float*)d_out;  // doubles as (N,B) scratch until final layer

    // CSR build for all 4 layers (independent of x)
    zero_counts_k<<<NLAYER * NNODE / 1024, 1024, 0, stream>>>();
    hist_k<<<NLAYER * NEDGE / 1024, 1024, 0, stream>>>(p0, p1, p2, p3);
    scan_block_k<<<NLAYER * SCAN_NBLK, SCAN_BLK, 0, stream>>>();
    scan_bsums_k<<<NLAYER, SCAN_NBLK, 0, stream>>>();
    scan_add_k<<<NLAYER * SCAN_NBLK, SCAN_BLK, 0, stream>>>();
    fill_k<<<NLAYER * NEDGE / 1024, 1024, 0, stream>>>(p0, p1, p2, p3);

    // x (B,N) -> OUT used as (N,B) scratch
    transpose_k<<<dim3(NNODE / 64, BATCH / 64), dim3(16, 16), 0, stream>>>(x, OUT, BATCH, NNODE);

    // g0: OUT->WS, g1: WS->OUT, g2: OUT->WS  (layers 0..2)
    gather_k<<<NNODE / 8, 512, 0, stream>>>((const float4*)OUT, (float4*)WS, 0);
    gather_k<<<NNODE / 8, 512, 0, stream>>>((const float4*)WS, (float4*)OUT, 1);
    gather_k<<<NNODE / 8, 512, 0, stream>>>((const float4*)OUT, (float4*)WS, 2);
    // g3 fused with transpose-back: WS (N,B) -> d_out (B,N)
    gather_tr_k<<<NNODE / 16, 512, 0, stream>>>((const float4*)WS, OUT, 3);
}

// Round 5
// 669.163 us; speedup vs baseline: 2.3296x; 1.0933x over previous
//
#include <hip/hip_runtime.h>
#include <hip/hip_bf16.h>

#define BATCH 512
#define NNODE 131072
#define NEDGE 131072
#define NLAYER 4
#define SCAN_BLK 1024
#define SCAN_NBLK (NNODE / SCAN_BLK)   // 128
#define PCAP (8 * NEDGE)               // per-pair entry capacity (expected ~4N)

// Per-layer CSR (application order: layer 0 = edges3 ... layer 3 = edges0)
__device__ int g_counts[NLAYER][NNODE];
__device__ int g_offs[NLAYER][NNODE];
__device__ int g_cursor[NLAYER][NNODE];
__device__ int g_srcl[NLAYER][NEDGE];
__device__ int g_bsums[NLAYER][SCAN_NBLK];

// Pair-combined CSR: pair0 = (I+A3)(I+A2), pair1 = (I+A1)(I+A0). Identity included.
__device__ int p_cnt[2][NNODE];
__device__ int p_offs[2][NNODE];
__device__ int p_srcl[2][PCAP];
__device__ int p_bsums[2][SCAN_NBLK];

// ---- 64x64 tiled transpose, float4 wide, 4 rows/thread. (R,C)->(C,R). blockDim (16,16).
__global__ void transpose_k(const float* __restrict__ in, float* __restrict__ out,
                            int R, int C) {
    __shared__ float tile[64][65];
    int c0 = blockIdx.x * 64;
    int r0 = blockIdx.y * 64;
    int tx = threadIdx.x;
    int ty = threadIdx.y;
    float4 v[4];
#pragma unroll
    for (int i = 0; i < 4; ++i)
        v[i] = *reinterpret_cast<const float4*>(&in[(size_t)(r0 + ty + 16 * i) * C + c0 + 4 * tx]);
#pragma unroll
    for (int i = 0; i < 4; ++i) {
        tile[ty + 16 * i][4 * tx + 0] = v[i].x;
        tile[ty + 16 * i][4 * tx + 1] = v[i].y;
        tile[ty + 16 * i][4 * tx + 2] = v[i].z;
        tile[ty + 16 * i][4 * tx + 3] = v[i].w;
    }
    __syncthreads();
#pragma unroll
    for (int i = 0; i < 4; ++i) {
        float4 w;
        w.x = tile[4 * tx + 0][ty + 16 * i];
        w.y = tile[4 * tx + 1][ty + 16 * i];
        w.z = tile[4 * tx + 2][ty + 16 * i];
        w.w = tile[4 * tx + 3][ty + 16 * i];
        *reinterpret_cast<float4*>(&out[(size_t)(c0 + ty + 16 * i) * R + r0 + 4 * tx]) = w;
    }
}

// ---- per-layer CSR build ----
__global__ void zero_counts_k() {
    int i = blockIdx.x * blockDim.x + threadIdx.x;
    ((int*)g_counts)[i] = 0;
}

__global__ void hist_k(const int* __restrict__ p0, const int* __restrict__ p1,
                       const int* __restrict__ p2, const int* __restrict__ p3) {
    int i = blockIdx.x * blockDim.x + threadIdx.x;
    int layer = i >> 17;
    int e = i & (NEDGE - 1);
    const int* eg = layer == 0 ? p0 : layer == 1 ? p1 : layer == 2 ? p2 : p3;
    atomicAdd(&g_counts[layer][eg[NEDGE + e]], 1);
}

__global__ void scan_block_k() {
    __shared__ int sh[SCAN_BLK];
    int layer = blockIdx.x / SCAN_NBLK;
    int blk = blockIdx.x % SCAN_NBLK;
    int t = threadIdx.x;
    int i = blk * SCAN_BLK + t;
    int own = g_counts[layer][i];
    sh[t] = own;
    __syncthreads();
    for (int off = 1; off < SCAN_BLK; off <<= 1) {
        int v = (t >= off) ? sh[t - off] : 0;
        __syncthreads();
        sh[t] += v;
        __syncthreads();
    }
    g_offs[layer][i] = sh[t] - own;
    if (t == SCAN_BLK - 1) g_bsums[layer][blk] = sh[t];
}

__global__ void scan_bsums_k() {
    __shared__ int sh[SCAN_NBLK];
    int layer = blockIdx.x;
    int t = threadIdx.x;
    int own = g_bsums[layer][t];
    sh[t] = own;
    __syncthreads();
    for (int off = 1; off < SCAN_NBLK; off <<= 1) {
        int v = (t >= off) ? sh[t - off] : 0;
        __syncthreads();
        sh[t] += v;
        __syncthreads();
    }
    g_bsums[layer][t] = sh[t] - own;
}

__global__ void scan_add_k() {
    int layer = blockIdx.x / SCAN_NBLK;
    int blk = blockIdx.x % SCAN_NBLK;
    int i = blk * SCAN_BLK + threadIdx.x;
    int o = g_offs[layer][i] + g_bsums[layer][blk];
    g_offs[layer][i] = o;
    g_cursor[layer][i] = o;
}

__global__ void fill_k(const int* __restrict__ p0, const int* __restrict__ p1,
                       const int* __restrict__ p2, const int* __restrict__ p3) {
    int i = blockIdx.x * blockDim.x + threadIdx.x;
    int layer = i >> 17;
    int e = i & (NEDGE - 1);
    const int* eg = layer == 0 ? p0 : layer == 1 ? p1 : layer == 2 ? p2 : p3;
    int s = eg[e];
    int d = eg[NEDGE + e];
    int p = atomicAdd(&g_cursor[layer][d], 1);
    g_srcl[layer][p] = s;
}

// ---- pair combine: P = (I+A_U)(I+A_V), col(d) = Ucol(d) + sum_{s in Vcol(d)} Ucol(s)
// where Ucol includes the identity. pair p uses U = layer 2p, V = layer 2p+1.
__global__ void count_pair_k() {
    int i = blockIdx.x * blockDim.x + threadIdx.x;  // 0..2N
    int pr = i >> 17;
    int d = i & (NNODE - 1);
    int U = pr * 2, V = pr * 2 + 1;
    int c = 1 + g_counts[U][d];
    int vb = g_offs[V][d], vd = g_counts[V][d];
    for (int j = 0; j < vd; ++j) {
        int s = g_srcl[V][vb + j];
        c += 1 + g_counts[U][s];
    }
    p_cnt[pr][d] = c;
}

__global__ void pscan_block_k() {
    __shared__ int sh[SCAN_BLK];
    int pr = blockIdx.x / SCAN_NBLK;
    int blk = blockIdx.x % SCAN_NBLK;
    int t = threadIdx.x;
    int i = blk * SCAN_BLK + t;
    int own = p_cnt[pr][i];
    sh[t] = own;
    __syncthreads();
    for (int off = 1; off < SCAN_BLK; off <<= 1) {
        int v = (t >= off) ? sh[t - off] : 0;
        __syncthreads();
        sh[t] += v;
        __syncthreads();
    }
    p_offs[pr][i] = sh[t] - own;
    if (t == SCAN_BLK - 1) p_bsums[pr][blk] = sh[t];
}

__global__ void pscan_bsums_k() {
    __shared__ int sh[SCAN_NBLK];
    int pr = blockIdx.x;
    int t = threadIdx.x;
    int own = p_bsums[pr][t];
    sh[t] = own;
    __syncthreads();
    for (int off = 1; off < SCAN_NBLK; off <<= 1) {
        int v = (t >= off) ? sh[t - off] : 0;
        __syncthreads();
        sh[t] += v;
        __syncthreads();
    }
    p_bsums[pr][t] = sh[t] - own;
}

__global__ void pscan_add_k() {
    int pr = blockIdx.x / SCAN_NBLK;
    int blk = blockIdx.x % SCAN_NBLK;
    int i = blk * SCAN_BLK + threadIdx.x;
    p_offs[pr][i] += p_bsums[pr][blk];
}

__global__ void fill_pair_k() {
    int i = blockIdx.x * blockDim.x + threadIdx.x;  // 0..2N
    int pr = i >> 17;
    int d = i & (NNODE - 1);
    int U = pr * 2, V = pr * 2 + 1;
    int p = p_offs[pr][d];
    int* buf = p_srcl[pr];
    buf[p++] = d;
    int ub = g_offs[U][d], ud = g_counts[U][d];
    for (int j = 0; j < ud; ++j) buf[p++] = g_srcl[U][ub + j];
    int vb = g_offs[V][d], vd = g_counts[V][d];
    for (int j = 0; j < vd; ++j) {
        int s = g_srcl[V][vb + j];
        buf[p++] = s;
        int sb = g_offs[U][s], sd = g_counts[U][s];
        for (int k = 0; k < sd; ++k) buf[p++] = g_srcl[U][sb + k];
    }
}

// ---- pair gather: 8 nodes per 512-thread block (one wave per node),
// identity is included in the list so acc starts at 0 ----
__global__ void gather_p_k(const float4* __restrict__ cur, float4* __restrict__ out,
                           int pr) {
    int t = threadIdx.x;
    int n = blockIdx.x * 8 + (t >> 6);
    int q = t & 63;
    int beg = p_offs[pr][n];
    int deg = p_cnt[pr][n];
    float4 a0 = {0.f, 0.f, 0.f, 0.f};
    float4 a1 = {0.f, 0.f, 0.f, 0.f};
    const int* sl = &p_srcl[pr][beg];
    for (int j = 0; j < deg; ++j) {
        size_t sb = (size_t)sl[j] * 128 + q;
        float4 v0 = cur[sb];
        float4 v1 = cur[sb + 64];
        a0.x += v0.x; a0.y += v0.y; a0.z += v0.z; a0.w += v0.w;
        a1.x += v1.x; a1.y += v1.y; a1.z += v1.z; a1.w += v1.w;
    }
    size_t base = (size_t)n * 128 + q;
    out[base] = a0;
    out[base + 64] = a1;
}

// ---- last pair gather fused with transpose-back. 1024 threads, 16 nodes/block.
// cur (N,B) float4 -> out (B,N) float. LDS float4 writes (conflict-free),
// padded row stride 129 float4 = 516 floats (read phase conflict-free).
__global__ void __launch_bounds__(1024) gather_tr_p_k(const float4* __restrict__ cur,
                                                      float* __restrict__ out, int pr) {
    __shared__ float4 lds4[16][129];
    int t = threadIdx.x;
    int n0 = blockIdx.x * 16;
    int nn = t >> 6;            // 0..15
    int q = t & 63;
    int n = n0 + nn;
    int beg = p_offs[pr][n];
    int deg = p_cnt[pr][n];
    float4 a0 = {0.f, 0.f, 0.f, 0.f};
    float4 a1 = {0.f, 0.f, 0.f, 0.f};
    const int* sl = &p_srcl[pr][beg];
    for (int j = 0; j < deg; ++j) {
        size_t sb = (size_t)sl[j] * 128 + q;
        float4 v0 = cur[sb];
        float4 v1 = cur[sb + 64];
        a0.x += v0.x; a0.y += v0.y; a0.z += v0.z; a0.w += v0.w;
        a1.x += v1.x; a1.y += v1.y; a1.z += v1.z; a1.w += v1.w;
    }
    lds4[nn][q] = a0;
    lds4[nn][64 + q] = a1;
    __syncthreads();
    if (t < BATCH) {
        int b = t;
        const float* f = (const float*)lds4;   // row stride 516 floats
        float4* orow = reinterpret_cast<float4*>(&out[(size_t)b * NNODE + n0]);
#pragma unroll
        for (int k = 0; k < 4; ++k) {
            float4 w;
            w.x = f[(4 * k + 0) * 516 + b];
            w.y = f[(4 * k + 1) * 516 + b];
            w.z = f[(4 * k + 2) * 516 + b];
            w.w = f[(4 * k + 3) * 516 + b];
            orow[k] = w;
        }
    }
}

extern "C" void kernel_launch(void* const* d_in, const int* in_sizes, int n_in,
                              void* d_out, int out_size, void* d_ws, size_t ws_size,
                              hipStream_t stream) {
    const float* x = (const float*)d_in[0];
    // Application order: edges3 (layer 0) ... edges0 (layer 3)
    const int* p0 = (const int*)d_in[4];
    const int* p1 = (const int*)d_in[3];
    const int* p2 = (const int*)d_in[2];
    const int* p3 = (const int*)d_in[1];

    float* WS = (float*)d_ws;    // (N,B) scratch (256 MB)
    float* OUT = (float*)d_out;  // doubles as (N,B) scratch until the final sweep

    // Per-layer CSR
    zero_counts_k<<<NLAYER * NNODE / 1024, 1024, 0, stream>>>();
    hist_k<<<NLAYER * NEDGE / 1024, 1024, 0, stream>>>(p0, p1, p2, p3);
    scan_block_k<<<NLAYER * SCAN_NBLK, SCAN_BLK, 0, stream>>>();
    scan_bsums_k<<<NLAYER, SCAN_NBLK, 0, stream>>>();
    scan_add_k<<<NLAYER * SCAN_NBLK, SCAN_BLK, 0, stream>>>();
    fill_k<<<NLAYER * NEDGE / 1024, 1024, 0, stream>>>(p0, p1, p2, p3);

    // Pair-combined CSR (2 pairs)
    count_pair_k<<<2 * NNODE / 1024, 1024, 0, stream>>>();
    pscan_block_k<<<2 * SCAN_NBLK, SCAN_BLK, 0, stream>>>();
    pscan_bsums_k<<<2, SCAN_NBLK, 0, stream>>>();
    pscan_add_k<<<2 * SCAN_NBLK, SCAN_BLK, 0, stream>>>();
    fill_pair_k<<<2 * NNODE / 256, 256, 0, stream>>>();

    // x (B,N) -> OUT used as (N,B) scratch
    transpose_k<<<dim3(NNODE / 64, BATCH / 64), dim3(16, 16), 0, stream>>>(x, OUT, BATCH, NNODE);

    // sweep 0 (pair 0): OUT -> WS
    gather_p_k<<<NNODE / 8, 512, 0, stream>>>((const float4*)OUT, (float4*)WS, 0);
    // sweep 1 (pair 1) fused with transpose-back: WS (N,B) -> d_out (B,N)
    gather_tr_p_k<<<NNODE / 16, 1024, 0, stream>>>((const float4*)WS, OUT, 1);
}

// Round 6
// 626.271 us; speedup vs baseline: 2.4892x; 1.0685x over previous
//
#include <hip/hip_runtime.h>
#include <hip/hip_bf16.h>

#define BATCH 512
#define NNODE 131072
#define NEDGE 131072
#define NLAYER 4
#define SCAN_BLK 1024
#define SCAN_NBLK (NNODE / SCAN_BLK)   // 128
#define PCAP (8 * NEDGE)               // per-pair entry capacity (expected ~4N)

// Per-layer CSR (application order: layer 0 = edges3 ... layer 3 = edges0)
__device__ int g_counts[NLAYER][NNODE];
__device__ int g_offs[NLAYER][NNODE];
__device__ int g_cursor[NLAYER][NNODE];
__device__ int g_srcl[NLAYER][NEDGE];
__device__ int g_bsums[NLAYER][SCAN_NBLK];

// Pair-combined CSR: pair0 = (I+A3)(I+A2), pair1 = (I+A1)(I+A0). Identity included.
__device__ int p_cnt[2][NNODE];
__device__ int p_offs[2][NNODE];
__device__ int p_srcl[2][PCAP];
__device__ int p_bsums[2][SCAN_NBLK];

#define ACC4(A0, A1, V0, V1)                                         \
    A0.x += V0.x; A0.y += V0.y; A0.z += V0.z; A0.w += V0.w;          \
    A1.x += V1.x; A1.y += V1.y; A1.z += V1.z; A1.w += V1.w;

// ---- 64x64 tiled transpose, float4 wide, 4 rows/thread. (R,C)->(C,R). blockDim (16,16).
__global__ void transpose_k(const float* __restrict__ in, float* __restrict__ out,
                            int R, int C) {
    __shared__ float tile[64][65];
    int c0 = blockIdx.x * 64;
    int r0 = blockIdx.y * 64;
    int tx = threadIdx.x;
    int ty = threadIdx.y;
    float4 v[4];
#pragma unroll
    for (int i = 0; i < 4; ++i)
        v[i] = *reinterpret_cast<const float4*>(&in[(size_t)(r0 + ty + 16 * i) * C + c0 + 4 * tx]);
#pragma unroll
    for (int i = 0; i < 4; ++i) {
        tile[ty + 16 * i][4 * tx + 0] = v[i].x;
        tile[ty + 16 * i][4 * tx + 1] = v[i].y;
        tile[ty + 16 * i][4 * tx + 2] = v[i].z;
        tile[ty + 16 * i][4 * tx + 3] = v[i].w;
    }
    __syncthreads();
#pragma unroll
    for (int i = 0; i < 4; ++i) {
        float4 w;
        w.x = tile[4 * tx + 0][ty + 16 * i];
        w.y = tile[4 * tx + 1][ty + 16 * i];
        w.z = tile[4 * tx + 2][ty + 16 * i];
        w.w = tile[4 * tx + 3][ty + 16 * i];
        *reinterpret_cast<float4*>(&out[(size_t)(c0 + ty + 16 * i) * R + r0 + 4 * tx]) = w;
    }
}

// ---- per-layer CSR build ----
__global__ void zero_counts_k() {
    int i = blockIdx.x * blockDim.x + threadIdx.x;
    ((int*)g_counts)[i] = 0;
}

__global__ void hist_k(const int* __restrict__ p0, const int* __restrict__ p1,
                       const int* __restrict__ p2, const int* __restrict__ p3) {
    int i = blockIdx.x * blockDim.x + threadIdx.x;
    int layer = i >> 17;
    int e = i & (NEDGE - 1);
    const int* eg = layer == 0 ? p0 : layer == 1 ? p1 : layer == 2 ? p2 : p3;
    atomicAdd(&g_counts[layer][eg[NEDGE + e]], 1);
}

__global__ void scan_block_k() {
    __shared__ int sh[SCAN_BLK];
    int layer = blockIdx.x / SCAN_NBLK;
    int blk = blockIdx.x % SCAN_NBLK;
    int t = threadIdx.x;
    int i = blk * SCAN_BLK + t;
    int own = g_counts[layer][i];
    sh[t] = own;
    __syncthreads();
    for (int off = 1; off < SCAN_BLK; off <<= 1) {
        int v = (t >= off) ? sh[t - off] : 0;
        __syncthreads();
        sh[t] += v;
        __syncthreads();
    }
    g_offs[layer][i] = sh[t] - own;
    if (t == SCAN_BLK - 1) g_bsums[layer][blk] = sh[t];
}

__global__ void scan_bsums_k() {
    __shared__ int sh[SCAN_NBLK];
    int layer = blockIdx.x;
    int t = threadIdx.x;
    int own = g_bsums[layer][t];
    sh[t] = own;
    __syncthreads();
    for (int off = 1; off < SCAN_NBLK; off <<= 1) {
        int v = (t >= off) ? sh[t - off] : 0;
        __syncthreads();
        sh[t] += v;
        __syncthreads();
    }
    g_bsums[layer][t] = sh[t] - own;
}

__global__ void scan_add_k() {
    int layer = blockIdx.x / SCAN_NBLK;
    int blk = blockIdx.x % SCAN_NBLK;
    int i = blk * SCAN_BLK + threadIdx.x;
    int o = g_offs[layer][i] + g_bsums[layer][blk];
    g_offs[layer][i] = o;
    g_cursor[layer][i] = o;
}

__global__ void fill_k(const int* __restrict__ p0, const int* __restrict__ p1,
                       const int* __restrict__ p2, const int* __restrict__ p3) {
    int i = blockIdx.x * blockDim.x + threadIdx.x;
    int layer = i >> 17;
    int e = i & (NEDGE - 1);
    const int* eg = layer == 0 ? p0 : layer == 1 ? p1 : layer == 2 ? p2 : p3;
    int s = eg[e];
    int d = eg[NEDGE + e];
    int p = atomicAdd(&g_cursor[layer][d], 1);
    g_srcl[layer][p] = s;
}

// ---- pair combine: P = (I+A_U)(I+A_V), col(d) = Ucol(d) + sum_{s in Vcol(d)} Ucol(s)
__global__ void count_pair_k() {
    int i = blockIdx.x * blockDim.x + threadIdx.x;  // 0..2N
    int pr = i >> 17;
    int d = i & (NNODE - 1);
    int U = pr * 2, V = pr * 2 + 1;
    int c = 1 + g_counts[U][d];
    int vb = g_offs[V][d], vd = g_counts[V][d];
    for (int j = 0; j < vd; ++j) {
        int s = g_srcl[V][vb + j];
        c += 1 + g_counts[U][s];
    }
    p_cnt[pr][d] = c;
}

__global__ void pscan_block_k() {
    __shared__ int sh[SCAN_BLK];
    int pr = blockIdx.x / SCAN_NBLK;
    int blk = blockIdx.x % SCAN_NBLK;
    int t = threadIdx.x;
    int i = blk * SCAN_BLK + t;
    int own = p_cnt[pr][i];
    sh[t] = own;
    __syncthreads();
    for (int off = 1; off < SCAN_BLK; off <<= 1) {
        int v = (t >= off) ? sh[t - off] : 0;
        __syncthreads();
        sh[t] += v;
        __syncthreads();
    }
    p_offs[pr][i] = sh[t] - own;
    if (t == SCAN_BLK - 1) p_bsums[pr][blk] = sh[t];
}

__global__ void pscan_bsums_k() {
    __shared__ int sh[SCAN_NBLK];
    int pr = blockIdx.x;
    int t = threadIdx.x;
    int own = p_bsums[pr][t];
    sh[t] = own;
    __syncthreads();
    for (int off = 1; off < SCAN_NBLK; off <<= 1) {
        int v = (t >= off) ? sh[t - off] : 0;
        __syncthreads();
        sh[t] += v;
        __syncthreads();
    }
    p_bsums[pr][t] = sh[t] - own;
}

__global__ void pscan_add_k() {
    int pr = blockIdx.x / SCAN_NBLK;
    int blk = blockIdx.x % SCAN_NBLK;
    int i = blk * SCAN_BLK + threadIdx.x;
    p_offs[pr][i] += p_bsums[pr][blk];
}

__global__ void fill_pair_k() {
    int i = blockIdx.x * blockDim.x + threadIdx.x;  // 0..2N
    int pr = i >> 17;
    int d = i & (NNODE - 1);
    int U = pr * 2, V = pr * 2 + 1;
    int p = p_offs[pr][d];
    int* buf = p_srcl[pr];
    buf[p++] = d;
    int ub = g_offs[U][d], ud = g_counts[U][d];
    for (int j = 0; j < ud; ++j) buf[p++] = g_srcl[U][ub + j];
    int vb = g_offs[V][d], vd = g_counts[V][d];
    for (int j = 0; j < vd; ++j) {
        int s = g_srcl[V][vb + j];
        buf[p++] = s;
        int sb = g_offs[U][s], sd = g_counts[U][s];
        for (int k = 0; k < sd; ++k) buf[p++] = g_srcl[U][sb + k];
    }
}

// Shared gather body: ×4-unrolled source loop, 4 independent accumulator sets.
__device__ __forceinline__ void gather_body(const float4* __restrict__ cur,
                                            const int* __restrict__ sl, int deg, int q,
                                            float4& o0, float4& o1) {
    float4 a0 = {0, 0, 0, 0}, a1 = {0, 0, 0, 0};
    float4 b0 = {0, 0, 0, 0}, b1 = {0, 0, 0, 0};
    float4 c0 = {0, 0, 0, 0}, c1 = {0, 0, 0, 0};
    float4 d0 = {0, 0, 0, 0}, d1 = {0, 0, 0, 0};
    int j = 0;
    for (; j + 4 <= deg; j += 4) {
        size_t s0 = (size_t)sl[j + 0] * 128 + q;
        size_t s1 = (size_t)sl[j + 1] * 128 + q;
        size_t s2 = (size_t)sl[j + 2] * 128 + q;
        size_t s3 = (size_t)sl[j + 3] * 128 + q;
        float4 v00 = cur[s0], v01 = cur[s0 + 64];
        float4 v10 = cur[s1], v11 = cur[s1 + 64];
        float4 v20 = cur[s2], v21 = cur[s2 + 64];
        float4 v30 = cur[s3], v31 = cur[s3 + 64];
        ACC4(a0, a1, v00, v01)
        ACC4(b0, b1, v10, v11)
        ACC4(c0, c1, v20, v21)
        ACC4(d0, d1, v30, v31)
    }
    for (; j < deg; ++j) {
        size_t s0 = (size_t)sl[j] * 128 + q;
        float4 v00 = cur[s0], v01 = cur[s0 + 64];
        ACC4(a0, a1, v00, v01)
    }
    o0.x = a0.x + b0.x + c0.x + d0.x;
    o0.y = a0.y + b0.y + c0.y + d0.y;
    o0.z = a0.z + b0.z + c0.z + d0.z;
    o0.w = a0.w + b0.w + c0.w + d0.w;
    o1.x = a1.x + b1.x + c1.x + d1.x;
    o1.y = a1.y + b1.y + c1.y + d1.y;
    o1.z = a1.z + b1.z + c1.z + d1.z;
    o1.w = a1.w + b1.w + c1.w + d1.w;
}

// ---- pair gather: 8 nodes per 512-thread block (one wave per node) ----
__global__ void gather_p_k(const float4* __restrict__ cur, float4* __restrict__ out,
                           int pr) {
    int t = threadIdx.x;
    int n = blockIdx.x * 8 + (t >> 6);
    int q = t & 63;
    int beg = p_offs[pr][n];
    int deg = p_cnt[pr][n];
    float4 o0, o1;
    gather_body(cur, &p_srcl[pr][beg], deg, q, o0, o1);
    size_t base = (size_t)n * 128 + q;
    out[base] = o0;
    out[base + 64] = o1;
}

// ---- last pair gather fused with transpose-back. 1024 threads, 16 nodes/block.
__global__ void __launch_bounds__(1024) gather_tr_p_k(const float4* __restrict__ cur,
                                                      float* __restrict__ out, int pr) {
    __shared__ float4 lds4[16][129];
    int t = threadIdx.x;
    int n0 = blockIdx.x * 16;
    int nn = t >> 6;            // 0..15
    int q = t & 63;
    int n = n0 + nn;
    int beg = p_offs[pr][n];
    int deg = p_cnt[pr][n];
    float4 o0, o1;
    gather_body(cur, &p_srcl[pr][beg], deg, q, o0, o1);
    lds4[nn][q] = o0;
    lds4[nn][64 + q] = o1;
    __syncthreads();
    if (t < BATCH) {
        int b = t;
        const float* f = (const float*)lds4;   // row stride 516 floats
        float4* orow = reinterpret_cast<float4*>(&out[(size_t)b * NNODE + n0]);
#pragma unroll
        for (int k = 0; k < 4; ++k) {
            float4 w;
            w.x = f[(4 * k + 0) * 516 + b];
            w.y = f[(4 * k + 1) * 516 + b];
            w.z = f[(4 * k + 2) * 516 + b];
            w.w = f[(4 * k + 3) * 516 + b];
            orow[k] = w;
        }
    }
}

extern "C" void kernel_launch(void* const* d_in, const int* in_sizes, int n_in,
                              void* d_out, int out_size, void* d_ws, size_t ws_size,
                              hipStream_t stream) {
    const float* x = (const float*)d_in[0];
    // Application order: edges3 (layer 0) ... edges0 (layer 3)
    const int* p0 = (const int*)d_in[4];
    const int* p1 = (const int*)d_in[3];
    const int* p2 = (const int*)d_in[2];
    const int* p3 = (const int*)d_in[1];

    float* WS = (float*)d_ws;    // (N,B) scratch (256 MB)
    float* OUT = (float*)d_out;  // doubles as (N,B) scratch until the final sweep

    // Per-layer CSR
    zero_counts_k<<<NLAYER * NNODE / 1024, 1024, 0, stream>>>();
    hist_k<<<NLAYER * NEDGE / 1024, 1024, 0, stream>>>(p0, p1, p2, p3);
    scan_block_k<<<NLAYER * SCAN_NBLK, SCAN_BLK, 0, stream>>>();
    scan_bsums_k<<<NLAYER, SCAN_NBLK, 0, stream>>>();
    scan_add_k<<<NLAYER * SCAN_NBLK, SCAN_BLK, 0, stream>>>();
    fill_k<<<NLAYER * NEDGE / 1024, 1024, 0, stream>>>(p0, p1, p2, p3);

    // Pair-combined CSR (2 pairs)
    count_pair_k<<<2 * NNODE / 1024, 1024, 0, stream>>>();
    pscan_block_k<<<2 * SCAN_NBLK, SCAN_BLK, 0, stream>>>();
    pscan_bsums_k<<<2, SCAN_NBLK, 0, stream>>>();
    pscan_add_k<<<2 * SCAN_NBLK, SCAN_BLK, 0, stream>>>();
    fill_pair_k<<<2 * NNODE / 256, 256, 0, stream>>>();

    // x (B,N) -> OUT used as (N,B) scratch
    transpose_k<<<dim3(NNODE / 64, BATCH / 64), dim3(16, 16), 0, stream>>>(x, OUT, BATCH, NNODE);

    // sweep 0 (pair 0): OUT -> WS
    gather_p_k<<<NNODE / 8, 512, 0, stream>>>((const float4*)OUT, (float4*)WS, 0);
    // sweep 1 (pair 1) fused with transpose-back: WS (N,B) -> d_out (B,N)
    gather_tr_p_k<<<NNODE / 16, 1024, 0, stream>>>((const float4*)WS, OUT, 1);
}

// Round 7
// 532.771 us; speedup vs baseline: 2.9260x; 1.1755x over previous
//
#include <hip/hip_runtime.h>
#include <hip/hip_bf16.h>

#define BATCH 512
#define NNODE 131072
#define NEDGE 131072
#define NLAYER 4
#define SCAN_BLK 1024
#define SCAN_NBLK (NNODE / SCAN_BLK)   // 128
#define PCAP (8 * NEDGE)               // per-pair entry capacity (expected ~4N)

// Per-layer CSR (application order: layer 0 = edges3 ... layer 3 = edges0)
__device__ int g_counts[NLAYER][NNODE];
__device__ int g_offs[NLAYER][NNODE];
__device__ int g_cursor[NLAYER][NNODE];
__device__ int g_srcl[NLAYER][NEDGE];
__device__ int g_bsums[NLAYER][SCAN_NBLK];

// Pair-combined CSR: pair0 = (I+A3)(I+A2), pair1 = (I+A1)(I+A0). Identity included.
__device__ int p_cnt[2][NNODE];
__device__ int p_offs[2][NNODE];
__device__ int p_srcl[2][PCAP];
__device__ int p_bsums[2][SCAN_NBLK];

// ---- per-layer CSR build ----
__global__ void zero_counts_k() {
    int i = blockIdx.x * blockDim.x + threadIdx.x;
    ((int*)g_counts)[i] = 0;
}

__global__ void hist_k(const int* __restrict__ p0, const int* __restrict__ p1,
                       const int* __restrict__ p2, const int* __restrict__ p3) {
    int i = blockIdx.x * blockDim.x + threadIdx.x;
    int layer = i >> 17;
    int e = i & (NEDGE - 1);
    const int* eg = layer == 0 ? p0 : layer == 1 ? p1 : layer == 2 ? p2 : p3;
    atomicAdd(&g_counts[layer][eg[NEDGE + e]], 1);
}

__global__ void scan_block_k() {
    __shared__ int sh[SCAN_BLK];
    int layer = blockIdx.x / SCAN_NBLK;
    int blk = blockIdx.x % SCAN_NBLK;
    int t = threadIdx.x;
    int i = blk * SCAN_BLK + t;
    int own = g_counts[layer][i];
    sh[t] = own;
    __syncthreads();
    for (int off = 1; off < SCAN_BLK; off <<= 1) {
        int v = (t >= off) ? sh[t - off] : 0;
        __syncthreads();
        sh[t] += v;
        __syncthreads();
    }
    g_offs[layer][i] = sh[t] - own;
    if (t == SCAN_BLK - 1) g_bsums[layer][blk] = sh[t];
}

__global__ void scan_bsums_k() {
    __shared__ int sh[SCAN_NBLK];
    int layer = blockIdx.x;
    int t = threadIdx.x;
    int own = g_bsums[layer][t];
    sh[t] = own;
    __syncthreads();
    for (int off = 1; off < SCAN_NBLK; off <<= 1) {
        int v = (t >= off) ? sh[t - off] : 0;
        __syncthreads();
        sh[t] += v;
        __syncthreads();
    }
    g_bsums[layer][t] = sh[t] - own;
}

__global__ void scan_add_k() {
    int layer = blockIdx.x / SCAN_NBLK;
    int blk = blockIdx.x % SCAN_NBLK;
    int i = blk * SCAN_BLK + threadIdx.x;
    int o = g_offs[layer][i] + g_bsums[layer][blk];
    g_offs[layer][i] = o;
    g_cursor[layer][i] = o;
}

__global__ void fill_k(const int* __restrict__ p0, const int* __restrict__ p1,
                       const int* __restrict__ p2, const int* __restrict__ p3) {
    int i = blockIdx.x * blockDim.x + threadIdx.x;
    int layer = i >> 17;
    int e = i & (NEDGE - 1);
    const int* eg = layer == 0 ? p0 : layer == 1 ? p1 : layer == 2 ? p2 : p3;
    int s = eg[e];
    int d = eg[NEDGE + e];
    int p = atomicAdd(&g_cursor[layer][d], 1);
    g_srcl[layer][p] = s;
}

// ---- pair combine: P = (I+A_U)(I+A_V), col(d) = Ucol(d) + sum_{s in Vcol(d)} Ucol(s)
__global__ void count_pair_k() {
    int i = blockIdx.x * blockDim.x + threadIdx.x;  // 0..2N
    int pr = i >> 17;
    int d = i & (NNODE - 1);
    int U = pr * 2, V = pr * 2 + 1;
    int c = 1 + g_counts[U][d];
    int vb = g_offs[V][d], vd = g_counts[V][d];
    for (int j = 0; j < vd; ++j) {
        int s = g_srcl[V][vb + j];
        c += 1 + g_counts[U][s];
    }
    p_cnt[pr][d] = c;
}

__global__ void pscan_block_k() {
    __shared__ int sh[SCAN_BLK];
    int pr = blockIdx.x / SCAN_NBLK;
    int blk = blockIdx.x % SCAN_NBLK;
    int t = threadIdx.x;
    int i = blk * SCAN_BLK + t;
    int own = p_cnt[pr][i];
    sh[t] = own;
    __syncthreads();
    for (int off = 1; off < SCAN_BLK; off <<= 1) {
        int v = (t >= off) ? sh[t - off] : 0;
        __syncthreads();
        sh[t] += v;
        __syncthreads();
    }
    p_offs[pr][i] = sh[t] - own;
    if (t == SCAN_BLK - 1) p_bsums[pr][blk] = sh[t];
}

__global__ void pscan_bsums_k() {
    __shared__ int sh[SCAN_NBLK];
    int pr = blockIdx.x;
    int t = threadIdx.x;
    int own = p_bsums[pr][t];
    sh[t] = own;
    __syncthreads();
    for (int off = 1; off < SCAN_NBLK; off <<= 1) {
        int v = (t >= off) ? sh[t - off] : 0;
        __syncthreads();
        sh[t] += v;
        __syncthreads();
    }
    p_bsums[pr][t] = sh[t] - own;
}

__global__ void pscan_add_k() {
    int pr = blockIdx.x / SCAN_NBLK;
    int blk = blockIdx.x % SCAN_NBLK;
    int i = blk * SCAN_BLK + threadIdx.x;
    p_offs[pr][i] += p_bsums[pr][blk];
}

__global__ void fill_pair_k() {
    int i = blockIdx.x * blockDim.x + threadIdx.x;  // 0..2N
    int pr = i >> 17;
    int d = i & (NNODE - 1);
    int U = pr * 2, V = pr * 2 + 1;
    int p = p_offs[pr][d];
    int* buf = p_srcl[pr];
    buf[p++] = d;
    int ub = g_offs[U][d], ud = g_counts[U][d];
    for (int j = 0; j < ud; ++j) buf[p++] = g_srcl[U][ub + j];
    int vb = g_offs[V][d], vd = g_counts[V][d];
    for (int j = 0; j < vd; ++j) {
        int s = g_srcl[V][vb + j];
        buf[p++] = s;
        int sb = g_offs[U][s], sd = g_counts[U][s];
        for (int k = 0; k < sd; ++k) buf[p++] = g_srcl[U][sb + k];
    }
}

// ---- transpose with bf16 output: x (B,N) f32 -> out (N,B) bf16. 64x64 tiles,
// blockDim (16,16), 4 rows/thread.
__global__ void transpose_bf_k(const float* __restrict__ in, unsigned short* __restrict__ out) {
    __shared__ float tile[64][65];
    int c0 = blockIdx.x * 64;   // N dim
    int r0 = blockIdx.y * 64;   // B dim
    int tx = threadIdx.x;
    int ty = threadIdx.y;
    float4 v[4];
#pragma unroll
    for (int i = 0; i < 4; ++i)
        v[i] = *reinterpret_cast<const float4*>(&in[(size_t)(r0 + ty + 16 * i) * NNODE + c0 + 4 * tx]);
#pragma unroll
    for (int i = 0; i < 4; ++i) {
        tile[ty + 16 * i][4 * tx + 0] = v[i].x;
        tile[ty + 16 * i][4 * tx + 1] = v[i].y;
        tile[ty + 16 * i][4 * tx + 2] = v[i].z;
        tile[ty + 16 * i][4 * tx + 3] = v[i].w;
    }
    __syncthreads();
#pragma unroll
    for (int i = 0; i < 4; ++i) {
        int n = c0 + ty + 16 * i;
        ushort4 w;
        __hip_bfloat16 h0 = __float2bfloat16(tile[4 * tx + 0][ty + 16 * i]);
        __hip_bfloat16 h1 = __float2bfloat16(tile[4 * tx + 1][ty + 16 * i]);
        __hip_bfloat16 h2 = __float2bfloat16(tile[4 * tx + 2][ty + 16 * i]);
        __hip_bfloat16 h3 = __float2bfloat16(tile[4 * tx + 3][ty + 16 * i]);
        w.x = *reinterpret_cast<unsigned short*>(&h0);
        w.y = *reinterpret_cast<unsigned short*>(&h1);
        w.z = *reinterpret_cast<unsigned short*>(&h2);
        w.w = *reinterpret_cast<unsigned short*>(&h3);
        *reinterpret_cast<ushort4*>(&out[(size_t)n * BATCH + r0 + 4 * tx]) = w;
    }
}

// bf16 unpack-accumulate: uint4 = 8 bf16 -> 8 f32 adds (bf16->f32 is a shift)
__device__ __forceinline__ void gacc8(float* a, uint4 v) {
    a[0] += __uint_as_float(v.x << 16);
    a[1] += __uint_as_float(v.x & 0xffff0000u);
    a[2] += __uint_as_float(v.y << 16);
    a[3] += __uint_as_float(v.y & 0xffff0000u);
    a[4] += __uint_as_float(v.z << 16);
    a[5] += __uint_as_float(v.z & 0xffff0000u);
    a[6] += __uint_as_float(v.w << 16);
    a[7] += __uint_as_float(v.w & 0xffff0000u);
}

__device__ __forceinline__ unsigned pack2(float lo, float hi) {
    __hip_bfloat16 l = __float2bfloat16(lo);
    __hip_bfloat16 h = __float2bfloat16(hi);
    return (unsigned)*reinterpret_cast<unsigned short*>(&l) |
           ((unsigned)*reinterpret_cast<unsigned short*>(&h) << 16);
}

// Shared gather body: cur is (N,B) bf16 as uint4 (64 per node). One lane load
// covers 8 batch elems; whole column = 1 wave-load. x4 unroll, 4 acc sets.
__device__ __forceinline__ void gather_body_bf(const uint4* __restrict__ cur,
                                               const int* __restrict__ sl, int deg, int q,
                                               float acc[8]) {
    float A[8] = {0, 0, 0, 0, 0, 0, 0, 0};
    float B_[8] = {0, 0, 0, 0, 0, 0, 0, 0};
    float C_[8] = {0, 0, 0, 0, 0, 0, 0, 0};
    float D_[8] = {0, 0, 0, 0, 0, 0, 0, 0};
    int j = 0;
    for (; j + 4 <= deg; j += 4) {
        uint4 v0 = cur[(size_t)sl[j + 0] * 64 + q];
        uint4 v1 = cur[(size_t)sl[j + 1] * 64 + q];
        uint4 v2 = cur[(size_t)sl[j + 2] * 64 + q];
        uint4 v3 = cur[(size_t)sl[j + 3] * 64 + q];
        gacc8(A, v0);
        gacc8(B_, v1);
        gacc8(C_, v2);
        gacc8(D_, v3);
    }
    for (; j < deg; ++j) {
        uint4 v = cur[(size_t)sl[j] * 64 + q];
        gacc8(A, v);
    }
#pragma unroll
    for (int k = 0; k < 8; ++k) acc[k] = A[k] + B_[k] + C_[k] + D_[k];
}

// ---- pair gather (bf16 -> bf16): 8 nodes per 512-thread block, one wave/node ----
__global__ void gather_p_k(const uint4* __restrict__ cur, uint4* __restrict__ out,
                           int pr) {
    int t = threadIdx.x;
    int n = blockIdx.x * 8 + (t >> 6);
    int q = t & 63;
    int beg = p_offs[pr][n];
    int deg = p_cnt[pr][n];
    float acc[8];
    gather_body_bf(cur, &p_srcl[pr][beg], deg, q, acc);
    uint4 w;
    w.x = pack2(acc[0], acc[1]);
    w.y = pack2(acc[2], acc[3]);
    w.z = pack2(acc[4], acc[5]);
    w.w = pack2(acc[6], acc[7]);
    out[(size_t)n * 64 + q] = w;
}

// ---- last pair gather (bf16 -> f32) fused with transpose-back.
// 1024 threads, 16 nodes/block (one wave/node). cur (N,B) bf16 -> out (B,N) f32.
__global__ void __launch_bounds__(1024) gather_tr_p_k(const uint4* __restrict__ cur,
                                                      float* __restrict__ out, int pr) {
    __shared__ float lds[16][520];
    int t = threadIdx.x;
    int n0 = blockIdx.x * 16;
    int nn = t >> 6;            // 0..15
    int q = t & 63;
    int n = n0 + nn;
    int beg = p_offs[pr][n];
    int deg = p_cnt[pr][n];
    float acc[8];
    gather_body_bf(cur, &p_srcl[pr][beg], deg, q, acc);
#pragma unroll
    for (int k = 0; k < 8; ++k) lds[nn][8 * q + k] = acc[k];
    __syncthreads();
    if (t < BATCH) {
        float4* orow = reinterpret_cast<float4*>(&out[(size_t)t * NNODE + n0]);
#pragma unroll
        for (int k = 0; k < 4; ++k) {
            float4 w;
            w.x = lds[4 * k + 0][t];
            w.y = lds[4 * k + 1][t];
            w.z = lds[4 * k + 2][t];
            w.w = lds[4 * k + 3][t];
            orow[k] = w;
        }
    }
}

extern "C" void kernel_launch(void* const* d_in, const int* in_sizes, int n_in,
                              void* d_out, int out_size, void* d_ws, size_t ws_size,
                              hipStream_t stream) {
    const float* x = (const float*)d_in[0];
    // Application order: edges3 (layer 0) ... edges0 (layer 3)
    const int* p0 = (const int*)d_in[4];
    const int* p1 = (const int*)d_in[3];
    const int* p2 = (const int*)d_in[2];
    const int* p3 = (const int*)d_in[1];

    // Two bf16 (N,B) buffers in d_ws: 128 MB each
    unsigned short* WS0 = (unsigned short*)d_ws;
    unsigned short* WS1 = WS0 + (size_t)NNODE * BATCH;
    float* OUT = (float*)d_out;

    // Per-layer CSR
    zero_counts_k<<<NLAYER * NNODE / 1024, 1024, 0, stream>>>();
    hist_k<<<NLAYER * NEDGE / 1024, 1024, 0, stream>>>(p0, p1, p2, p3);
    scan_block_k<<<NLAYER * SCAN_NBLK, SCAN_BLK, 0, stream>>>();
    scan_bsums_k<<<NLAYER, SCAN_NBLK, 0, stream>>>();
    scan_add_k<<<NLAYER * SCAN_NBLK, SCAN_BLK, 0, stream>>>();
    fill_k<<<NLAYER * NEDGE / 1024, 1024, 0, stream>>>(p0, p1, p2, p3);

    // Pair-combined CSR (2 pairs)
    count_pair_k<<<2 * NNODE / 1024, 1024, 0, stream>>>();
    pscan_block_k<<<2 * SCAN_NBLK, SCAN_BLK, 0, stream>>>();
    pscan_bsums_k<<<2, SCAN_NBLK, 0, stream>>>();
    pscan_add_k<<<2 * SCAN_NBLK, SCAN_BLK, 0, stream>>>();
    fill_pair_k<<<2 * NNODE / 256, 256, 0, stream>>>();

    // x (B,N) f32 -> WS0 (N,B) bf16
    transpose_bf_k<<<dim3(NNODE / 64, BATCH / 64), dim3(16, 16), 0, stream>>>(x, WS0);

    // sweep 0 (pair 0): WS0 -> WS1 (bf16)
    gather_p_k<<<NNODE / 8, 512, 0, stream>>>((const uint4*)WS0, (uint4*)WS1, 0);
    // sweep 1 (pair 1) fused with transpose-back: WS1 (N,B) bf16 -> d_out (B,N) f32
    gather_tr_p_k<<<NNODE / 16, 1024, 0, stream>>>((const uint4*)WS1, OUT, 1);
}